// Round 6
// baseline (1019.795 us; speedup 1.0000x reference)
//
#include <hip/hip_runtime.h>
#include <stdint.h>

#define BB 8
#define SD 512

typedef unsigned short u16;
typedef __attribute__((ext_vector_type(8))) __bf16 bf16x8;
typedef __attribute__((ext_vector_type(4))) float f32x4;

// Static device scratch
__device__ float g_s[BB * 128];
__device__ u16 g_wtb[BB * 9 * 2 * 8192];   // [b][tap][chunk]: 16KB blocks, swizzled [co][ci64^((co&7)<<3)]

typedef const __attribute__((address_space(1))) uint32_t* gp1;
typedef __attribute__((address_space(3))) uint32_t* lp3;

__device__ __forceinline__ void glds16(const void* g, void* l) {
    __builtin_amdgcn_global_load_lds((gp1)g, (lp3)l, 16, 0, 0);
}

__device__ __forceinline__ u16 f2bf(float f) {
    uint32_t u = __float_as_uint(f);
    u += 0x7FFFu + ((u >> 16) & 1u);   // RNE
    return (u16)(u >> 16);
}

__global__ void affine_kernel(const float* __restrict__ style,
                              const float* __restrict__ aff_w,
                              const float* __restrict__ aff_b) {
    int b = blockIdx.x;
    int ci = threadIdx.x;
    const float gain = 0.044194173824159216f;  // 1/sqrt(512)
    const float* st = style + b * SD;
    const float* aw = aff_w + ci * SD;
    float acc = 0.f;
    #pragma unroll 8
    for (int j = 0; j < SD; ++j) acc += st[j] * aw[j];
    g_s[b * 128 + ci] = acc * gain + aff_b[ci];
}

__global__ __launch_bounds__(256) void modulate_kernel(const float* __restrict__ w_base) {
    int blk = blockIdx.x;           // 0..B*CO-1
    int b = blk >> 7, co = blk & 127;
    int tid = threadIdx.x;
    const float wgain = 0.029462782549439483f;  // 1/sqrt(128*9)
    const int n = 1152;
    const float* wb = w_base + co * n;
    const float* sp = g_s + b * 128;

    float v[5];
    float sq = 0.f;
    #pragma unroll
    for (int i = 0; i < 5; ++i) {
        int idx = tid + i * 256;
        float w = 0.f;
        if (idx < n) {
            int ci = idx / 9;
            w = wb[idx] * wgain * sp[ci];
        }
        v[i] = w;
        sq += w * w;
    }
    #pragma unroll
    for (int off = 32; off > 0; off >>= 1) sq += __shfl_down(sq, off, 64);
    __shared__ float red[4];
    int lane = tid & 63, wvi = tid >> 6;
    if (lane == 0) red[wvi] = sq;
    __syncthreads();
    float tot = red[0] + red[1] + red[2] + red[3];
    float d = rsqrtf(tot + 1e-8f);
    #pragma unroll
    for (int i = 0; i < 5; ++i) {
        int idx = tid + i * 256;
        if (idx < n) {
            int ci = idx / 9;
            int k9 = idx - ci * 9;              // tap
            u16 hv = f2bf(v[i] * d);
            int ci64 = ci & 63;
            size_t base = ((size_t)(b * 9 + k9) * 2 + (ci >> 6)) * 8192;
            g_wtb[base + co * 64 + (ci64 ^ ((co & 7) << 3))] = hv;
        }
    }
}

// Fused implicit-GEMM conv: per block: batch b, 32x8 px tile, all 128 co. 512 threads.
// X staged directly from fp32 x (no pre-transpose), ci-halves -> 74.5 KB LDS -> 2 blocks/CU.
__global__ __launch_bounds__(512, 4) void conv_kernel(const float* __restrict__ x,
                                                      float* __restrict__ y) {
    __shared__ __align__(16) u16 xs[10 * 34 * 64];    // [row][col][ci-half] 43520 B, swizzled
    __shared__ __align__(16) u16 ab[2][8192];         // A double buffer, 2x16 KB

    const int b = blockIdx.y;
    const int t = blockIdx.x;                 // 0..255
    const int swzt = (t & 7) * 32 + (t >> 3); // XCD-aware swizzle (256 % 8 == 0)
    const int tx = swzt & 7, ty = swzt >> 3;
    const int y0 = ty * 8, x0 = tx * 32;
    const int tid = threadIdx.x;
    const int lane = tid & 63, wv = tid >> 6;
    const int kgrp = lane >> 4, lp = lane & 15;
    const int coBase = (wv & 1) * 64;         // wave co origin
    const int py0w = (wv >> 1) * 2;           // wave row origin (2 rows/wave)

    const char* wtbB = (const char*)(g_wtb) + (size_t)b * 294912;
    char* xsB = (char*)xs;

    f32x4 acc[4][4];
    #pragma unroll
    for (int mf = 0; mf < 4; ++mf)
        #pragma unroll
        for (int nf = 0; nf < 4; ++nf)
            acc[mf][nf] = (f32x4){0.f, 0.f, 0.f, 0.f};

    const int aswz = (lp & 7) << 4;
    const int abase = (coBase + lp) * 128;

    for (int h = 0; h < 2; ++h) {
        if (h == 0) {
            // stage A step 0 (tap 0, chunk 0) early — async into LDS
            #pragma unroll
            for (int q = 0; q < 2; ++q) {
                int j = wv * 2 + q;
                glds16(wtbB + j * 1024 + lane * 16, (char*)ab[0] + j * 1024);
            }
        }
        // ---- stage X ci-half h directly from x: 11520 float2 over 512 threads ----
        {
            const float* xh = x + (size_t)(b * 128 + h * 64) * 65536;
            #pragma unroll
            for (int batch = 0; batch < 3; ++batch) {
                float2 v[8];
                #pragma unroll
                for (int j = 0; j < 8; ++j) {
                    int i = tid + (batch * 8 + j) * 512;
                    float2 val = make_float2(0.f, 0.f);
                    if (i < 11520) {
                        int seg = i % 18;
                        int rest = i / 18;        // 0..639
                        int ci = rest & 63;
                        int r = rest >> 6;        // 0..9
                        int gy = y0 - 1 + r;
                        int gx0 = x0 - 2 + seg * 2;
                        if ((unsigned)gy < 256u && (unsigned)gx0 < 256u)
                            val = *(const float2*)(xh + (size_t)ci * 65536 + gy * 256 + gx0);
                    }
                    v[j] = val;
                }
                #pragma unroll
                for (int j = 0; j < 8; ++j) {
                    int i = tid + (batch * 8 + j) * 512;
                    if (i < 11520) {
                        int seg = i % 18;
                        int rest = i / 18;
                        int ci = rest & 63;
                        int r = rest >> 6;
                        int g = ci >> 3, sub = (ci & 7) * 2;
                        const float* pv = (const float*)&v[j];
                        #pragma unroll
                        for (int e = 0; e < 2; ++e) {
                            int c = seg * 2 - 1 + e;    // xs col, -1..34
                            if ((unsigned)c < 34u) {
                                int key = (x0 + c) & 7;
                                int byte = (r * 34 + c) * 128 + ((g ^ key) * 16 + sub);
                                *(u16*)(xsB + byte) = f2bf(pv[e]);
                            }
                        }
                    }
                }
            }
        }
        __syncthreads();

        for (int tap = 0; tap < 9; ++tap) {
            int s = h * 9 + tap;
            if (s < 17) {
                // prefetch next A block: index = ntap*2 + nh
                int ns = s + 1;
                int ntap = (ns >= 9) ? (ns - 9) : ns;
                int nh = (ns >= 9) ? 1 : 0;
                const char* src = wtbB + (ntap * 2 + nh) * 16384;
                char* dst = (char*)ab[ns & 1];
                #pragma unroll
                for (int q = 0; q < 2; ++q) {
                    int j = wv * 2 + q;
                    glds16(src + j * 1024 + lane * 16, dst + j * 1024);
                }
            }

            const int ky = tap / 3, kx = tap - ky * 3;
            const char* abuf = (const char*)ab[s & 1];

            #pragma unroll
            for (int ks = 0; ks < 2; ++ks) {
                const int ka = (ks * 64 + kgrp * 16) ^ aswz;
                bf16x8 af[4];
                #pragma unroll
                for (int mf = 0; mf < 4; ++mf)
                    af[mf] = *(const bf16x8*)(abuf + abase + mf * 2048 + ka);
                bf16x8 bfv[4];
                #pragma unroll
                for (int nf = 0; nf < 4; ++nf) {
                    int ccol = (nf & 1) * 16 + lp + kx;
                    int brow = py0w + (nf >> 1) + ky;
                    int kb = (ks * 64 + kgrp * 16) ^ ((ccol & 7) << 4);
                    bfv[nf] = *(const bf16x8*)(xsB + (brow * 34 + ccol) * 128 + kb);
                }
                __builtin_amdgcn_s_setprio(1);
                #pragma unroll
                for (int mf = 0; mf < 4; ++mf)
                    #pragma unroll
                    for (int nf = 0; nf < 4; ++nf)
                        acc[mf][nf] = __builtin_amdgcn_mfma_f32_16x16x32_bf16(
                            af[mf], bfv[nf], acc[mf][nf], 0, 0, 0);
                __builtin_amdgcn_s_setprio(0);
            }
            __syncthreads();
        }
    }

    // ---- epilogue: nf pairs cover cols 0..31 -> full 128-B lines per (co,row) ----
    float* yb = y + (size_t)b * 128 * 65536;
    #pragma unroll
    for (int mf = 0; mf < 4; ++mf) {
        #pragma unroll
        for (int nf = 0; nf < 4; ++nf) {
            int gy = y0 + py0w + (nf >> 1);
            int gx = x0 + (nf & 1) * 16 + lp;
            #pragma unroll
            for (int r = 0; r < 4; ++r) {
                int co = coBase + mf * 16 + kgrp * 4 + r;
                yb[(size_t)co * 65536 + gy * 256 + gx] = acc[mf][nf][r];
            }
        }
    }
}

extern "C" void kernel_launch(void* const* d_in, const int* in_sizes, int n_in,
                              void* d_out, int out_size, void* d_ws, size_t ws_size,
                              hipStream_t stream) {
    const float* x = (const float*)d_in[0];
    const float* style = (const float*)d_in[1];
    const float* w_base = (const float*)d_in[2];
    const float* aff_w = (const float*)d_in[3];
    const float* aff_b = (const float*)d_in[4];
    float* y = (float*)d_out;

    affine_kernel<<<BB, 128, 0, stream>>>(style, aff_w, aff_b);
    modulate_kernel<<<BB * 128, 256, 0, stream>>>(w_base);
    conv_kernel<<<dim3(256, BB), 512, 0, stream>>>(x, y);
}

// Round 7
// 326.523 us; speedup vs baseline: 3.1232x; 3.1232x over previous
//
#include <hip/hip_runtime.h>
#include <stdint.h>

#define BB 8
#define SD 512

typedef unsigned short u16;
typedef __attribute__((ext_vector_type(8))) __bf16 bf16x8;
typedef __attribute__((ext_vector_type(16))) float f32x16;

// Static device scratch
__device__ float g_s[BB * 128];
__device__ u16 g_wtb[BB * 9 * 2 * 8192];                  // [b][tap][chunk]: 16KB blocks, swizzled
__device__ u16 g_xb[(size_t)BB * 258 * 258 * 128 + 2048]; // [b][gy_p][gx_p][ci] bf16, swizzled per pixel

typedef const __attribute__((address_space(1))) uint32_t* gp1;
typedef __attribute__((address_space(3))) uint32_t* lp3;

__device__ __forceinline__ void glds16(const void* g, void* l) {
    __builtin_amdgcn_global_load_lds((gp1)g, (lp3)l, 16, 0, 0);
}
__device__ __forceinline__ void glds4(const void* g, void* l) {
    __builtin_amdgcn_global_load_lds((gp1)g, (lp3)l, 4, 0, 0);
}

__device__ __forceinline__ u16 f2bf(float f) {
    uint32_t u = __float_as_uint(f);
    u += 0x7FFFu + ((u >> 16) & 1u);   // RNE
    return (u16)(u >> 16);
}

__global__ void affine_kernel(const float* __restrict__ style,
                              const float* __restrict__ aff_w,
                              const float* __restrict__ aff_b) {
    int b = blockIdx.x;
    int ci = threadIdx.x;
    const float gain = 0.044194173824159216f;  // 1/sqrt(512)
    const float* st = style + b * SD;
    const float* aw = aff_w + ci * SD;
    float acc = 0.f;
    #pragma unroll 8
    for (int j = 0; j < SD; ++j) acc += st[j] * aw[j];
    g_s[b * 128 + ci] = acc * gain + aff_b[ci];
}

__global__ __launch_bounds__(256) void modulate_kernel(const float* __restrict__ w_base) {
    int blk = blockIdx.x;           // 0..B*CO-1
    int b = blk >> 7, co = blk & 127;
    int tid = threadIdx.x;
    const float wgain = 0.029462782549439483f;  // 1/sqrt(128*9)
    const int n = 1152;
    const float* wb = w_base + co * n;
    const float* sp = g_s + b * 128;

    float v[5];
    float sq = 0.f;
    #pragma unroll
    for (int i = 0; i < 5; ++i) {
        int idx = tid + i * 256;
        float w = 0.f;
        if (idx < n) {
            int ci = idx / 9;
            w = wb[idx] * wgain * sp[ci];
        }
        v[i] = w;
        sq += w * w;
    }
    #pragma unroll
    for (int off = 32; off > 0; off >>= 1) sq += __shfl_down(sq, off, 64);
    __shared__ float red[4];
    int lane = tid & 63, wvi = tid >> 6;
    if (lane == 0) red[wvi] = sq;
    __syncthreads();
    float tot = red[0] + red[1] + red[2] + red[3];
    float d = rsqrtf(tot + 1e-8f);
    #pragma unroll
    for (int i = 0; i < 5; ++i) {
        int idx = tid + i * 256;
        if (idx < n) {
            int ci = idx / 9;
            int k9 = idx - ci * 9;              // tap
            u16 hv = f2bf(v[i] * d);
            int ci64 = ci & 63;
            // swizzled u16 index: co*64 + (ci64 ^ ((co&7)<<3))
            size_t base = ((size_t)(b * 9 + k9) * 2 + (ci >> 6)) * 8192;
            g_wtb[base + co * 64 + (ci64 ^ ((co & 7) << 3))] = hv;
        }
    }
}

// zero halo borders of g_xb
__global__ __launch_bounds__(256) void zero_border_kernel() {
    int b = blockIdx.x;
    uint4 z = make_uint4(0, 0, 0, 0);
    char* xbB = (char*)g_xb;
    for (int i = threadIdx.x; i < 16448; i += 256) {
        size_t pix; int k;
        if (i < 4128)       { pix = (size_t)(b * 258 + 0)   * 258 + (i >> 4);            k = i & 15; }
        else if (i < 8256)  { int j = i - 4128;  pix = (size_t)(b * 258 + 257) * 258 + (j >> 4);       k = j & 15; }
        else if (i < 12352) { int j = i - 8256;  pix = (size_t)(b * 258 + 1 + (j >> 4)) * 258 + 0;     k = j & 15; }
        else                { int j = i - 12352; pix = (size_t)(b * 258 + 1 + (j >> 4)) * 258 + 257;   k = j & 15; }
        *(uint4*)(xbB + pix * 256 + (size_t)k * 16) = z;
    }
}

// transpose+convert v2: x [b][ci][h][w] fp32 -> g_xb [b][h+1][w+1][ci] bf16 (swizzled)
__global__ __launch_bounds__(256) void transpose_kernel(const float* __restrict__ x) {
    __shared__ __align__(16) u16 t_lds[64 * 128];   // 16 KB
    const int chunk = blockIdx.x;        // 0..3 (64-px chunk)
    const int gy = blockIdx.y;           // 0..255
    const int b = blockIdx.z;
    const int px0 = chunk * 64;
    const int tid = threadIdx.x;
    const int pq = tid & 15;             // pixel quad: px = px0 + pq*4 + j
    const int cig = tid >> 4;            // 16-B ci group (8 ci), 0..15

    const float* base = x + (size_t)b * 128 * 65536 + (size_t)gy * 256 + px0 + pq * 4;
    char* ldsB = (char*)t_lds;

    float4 v[8];
    #pragma unroll
    for (int c = 0; c < 8; ++c)
        v[c] = *(const float4*)(base + (size_t)(cig * 8 + c) * 65536);

    #pragma unroll
    for (int j = 0; j < 4; ++j) {
        uint32_t dw[4];
        #pragma unroll
        for (int d = 0; d < 4; ++d) {
            const float* lo4 = (const float*)&v[2 * d];
            const float* hi4 = (const float*)&v[2 * d + 1];
            dw[d] = (uint32_t)f2bf(lo4[j]) | ((uint32_t)f2bf(hi4[j]) << 16);
        }
        int px = pq * 4 + j;                 // within chunk
        int key = (px0 + px + 1) & 7;        // (gx_p)&7
        int slot = cig ^ key;
        *(uint4*)(ldsB + px * 256 + slot * 16) = *(uint4*)dw;
    }
    __syncthreads();

    char* outB = (char*)g_xb;
    #pragma unroll
    for (int it = 0; it < 4; ++it) {
        int flat = it * 256 + tid;
        int r = flat >> 4, k = flat & 15;
        size_t pix = ((size_t)(b * 258 + gy + 1)) * 258 + (px0 + r + 1);
        *(uint4*)(outB + pix * 256 + k * 16) = *(const uint4*)(ldsB + r * 256 + k * 16);
    }
}

// Implicit-GEMM conv: per block: batch b, 32x8 px tile, all 128 co. 512 threads.
// 32x32x16 MFMA, X staged in ci-halves from g_xb -> 74.5 KB LDS -> 2 blocks/CU.
__global__ __launch_bounds__(512, 4) void conv_kernel(float* __restrict__ y) {
    __shared__ __align__(16) u16 xs[10 * 34 * 64];    // [row][col][ci-half] 43520 B
    __shared__ __align__(16) u16 ab[2][8192];         // A double buffer, 2x16 KB

    const int b = blockIdx.y;
    const int t = blockIdx.x;                 // 0..255
    const int swzt = (t & 7) * 32 + (t >> 3); // XCD-aware swizzle (256 % 8 == 0)
    const int tx = swzt & 7, ty = swzt >> 3;
    const int y0 = ty * 8, x0 = tx * 32;
    const int tid = threadIdx.x;
    const int lane = tid & 63, wv = tid >> 6;
    const int l31 = lane & 31;                // px-col / co-row within MFMA tile
    const int l5 = lane >> 5;                 // k-group select
    const int coHalf = (wv & 1) * 64;         // wave co origin
    const int py0w = (wv >> 1) * 2;           // wave row origin (2 rows/wave)

    const char* xbB = (const char*)g_xb;
    const char* wtbB = (const char*)(g_wtb) + (size_t)b * 294912;
    char* xsB = (char*)xs;

    f32x16 acc[2][2];
    #pragma unroll
    for (int mf = 0; mf < 2; ++mf)
        #pragma unroll
        for (int rf = 0; rf < 2; ++rf)
            acc[mf][rf] = (f32x16){0.f};

    for (int h = 0; h < 2; ++h) {
        // ---- stage X ci-half h from g_xb: 10 rows x (4 glds16 + 1 glds4) ----
        for (int i = wv; i < 50; i += 8) {
            int row = i / 5, sub = i - row * 5;
            size_t pixb = ((size_t)(b * 258 + y0 + row) * 258 + x0) * 256 + h * 128;
            char* dst = xsB + row * 4352;
            if (sub < 4) {
                // 8 px per inst: lane l -> px c = sub*8 + l/8, byte (l&7)*16 within 128B half
                glds16(xbB + pixb + (size_t)(sub * 8 + (lane >> 3)) * 256 + (lane & 7) * 16,
                       dst + sub * 1024);
            } else {
                // last 2 px: lane l -> px 32 + l/32, byte (l&31)*4
                glds4(xbB + pixb + (size_t)(32 + (lane >> 5)) * 256 + (lane & 31) * 4,
                      dst + 4096);
            }
        }
        if (h == 0) {
            // stage A step 0 (tap 0, chunk 0)
            #pragma unroll
            for (int q = 0; q < 2; ++q) {
                int j = wv * 2 + q;
                glds16(wtbB + j * 1024 + lane * 16, (char*)ab[0] + j * 1024);
            }
        }
        __syncthreads();

        for (int tap = 0; tap < 9; ++tap) {
            int s = h * 9 + tap;
            if (s < 17) {
                int ns = s + 1;
                int ntap = (ns >= 9) ? (ns - 9) : ns;
                int nh = (ns >= 9) ? 1 : h;
                const char* src = wtbB + (ntap * 2 + nh) * 16384;
                char* dst = (char*)ab[ns & 1];
                #pragma unroll
                for (int q = 0; q < 2; ++q) {
                    int j = wv * 2 + q;
                    glds16(src + j * 1024 + lane * 16, dst + j * 1024);
                }
            }

            const int ky = tap / 3, kx = tap - ky * 3;
            const char* abuf = (const char*)ab[s & 1];
            const int bcol = l31 + kx;                 // xs col 0..33
            const int bkey = bcol & 7;                 // x0 % 8 == 0
            const int brow_base = (py0w + ky) * 34 + bcol;

            #pragma unroll
            for (int ks = 0; ks < 4; ++ks) {           // K = 64 per half, steps of 16
                const int cig = ks * 2 + l5;           // 16B-slot 0..7
                bf16x8 af[2];
                #pragma unroll
                for (int mf = 0; mf < 2; ++mf) {
                    int co = coHalf + mf * 32 + l31;
                    af[mf] = *(const bf16x8*)(abuf + co * 128 + ((cig ^ (co & 7)) << 4));
                }
                bf16x8 bf[2];
                #pragma unroll
                for (int rf = 0; rf < 2; ++rf)
                    bf[rf] = *(const bf16x8*)(xsB + (brow_base + rf * 34) * 128 +
                                              ((cig ^ bkey) << 4));
                __builtin_amdgcn_s_setprio(1);
                #pragma unroll
                for (int mf = 0; mf < 2; ++mf)
                    #pragma unroll
                    for (int rf = 0; rf < 2; ++rf)
                        acc[mf][rf] = __builtin_amdgcn_mfma_f32_32x32x16_bf16(
                            af[mf], bf[rf], acc[mf][rf], 0, 0, 0);
                __builtin_amdgcn_s_setprio(0);
            }
            __syncthreads();
        }
    }

    // ---- epilogue: C layout (32x32): col = lane&31, row = (j&3)+8*(j>>2)+4*(lane>>5) ----
    float* yb = y + (size_t)b * 128 * 65536;
    #pragma unroll
    for (int mf = 0; mf < 2; ++mf) {
        #pragma unroll
        for (int rf = 0; rf < 2; ++rf) {
            int gy = y0 + py0w + rf;
            int gx = x0 + l31;
            #pragma unroll
            for (int j = 0; j < 16; ++j) {
                int co = coHalf + mf * 32 + (j & 3) + 8 * (j >> 2) + 4 * l5;
                yb[(size_t)co * 65536 + gy * 256 + gx] = acc[mf][rf][j];
            }
        }
    }
}

extern "C" void kernel_launch(void* const* d_in, const int* in_sizes, int n_in,
                              void* d_out, int out_size, void* d_ws, size_t ws_size,
                              hipStream_t stream) {
    const float* x = (const float*)d_in[0];
    const float* style = (const float*)d_in[1];
    const float* w_base = (const float*)d_in[2];
    const float* aff_w = (const float*)d_in[3];
    const float* aff_b = (const float*)d_in[4];
    float* y = (float*)d_out;

    affine_kernel<<<BB, 128, 0, stream>>>(style, aff_w, aff_b);
    modulate_kernel<<<BB * 128, 256, 0, stream>>>(w_base);
    zero_border_kernel<<<BB, 256, 0, stream>>>();
    transpose_kernel<<<dim3(4, 256, BB), 256, 0, stream>>>(x);
    conv_kernel<<<dim3(256, BB), 512, 0, stream>>>(y);
}